// Round 4
// baseline (806.998 us; speedup 1.0000x reference)
//
#include <hip/hip_runtime.h>
#include <hip/hip_bf16.h>
#include <stdint.h>

#define EPS 1e-8f

typedef __attribute__((ext_vector_type(8))) short bf16x8;
typedef __attribute__((ext_vector_type(4))) float f32x4;
typedef unsigned long long u64;
typedef unsigned int u32;

constexpr int SEQ = 200;
constexpr int B_  = 1024;    // batch
constexpr int D_  = 300;     // embedding dim
constexpr int DP  = 320;     // K padded
constexpr int NT  = 100000;  // train rows
constexpr int BM = 256, BN = 128, BK = 64;
constexpr int NSTRIP = 784;            // N strips (128 wide), multiple of 8
constexpr int NTP = NSTRIP * BN;       // 100352 padded rows
constexpr int POOL_BLOCKS = B_;        // 1024
constexpr int TN_BLOCKS = (NTP + 4) / 5;   // 20071 (5 rows/block)
#define MARGIN 2e-3f

__device__ __forceinline__ unsigned short f2bf(float f) {   // RNE
    u32 b = __float_as_uint(f);
    return (unsigned short)((b + 0x7fffu + ((b >> 16) & 1u)) >> 16);
}
__device__ __forceinline__ u32 simkey(float s) {            // order-preserving
    u32 b = __float_as_uint(s);
    return (b & 0x80000000u) ? ~b : (b | 0x80000000u);
}
__device__ __forceinline__ float keysim(u32 k) {
    u32 b = (k & 0x80000000u) ? (k & 0x7fffffffu) : ~k;
    return __uint_as_float(b);
}
__device__ __forceinline__ void gload_lds16(const void* g, void* l) {
    __builtin_amdgcn_global_load_lds(
        (const __attribute__((address_space(1))) unsigned int*)g,
        (__attribute__((address_space(3))) unsigned int*)l, 16, 0, 0);
}

// ---------------------------------------------------------------------------
// K1 "prep": fused pool (blocks 0..1023) + tnorm/convert (rest).
// Pool: 4 accumulator chains, writes x fp32, xh bf16 (RNE, cols 300..319=0),
// 1/max(||x||,eps). Tnorm: 5 rows/block (wave per row), writes rtn + Tb bf16
// (rows/cols zero-padded).
// ---------------------------------------------------------------------------
__global__ __launch_bounds__(320) void prep_kernel(
    const int* __restrict__ ids, const float* __restrict__ W,
    const float* __restrict__ T,
    float* __restrict__ x, unsigned short* __restrict__ xh,
    float* __restrict__ rxn, float* __restrict__ rtn,
    unsigned short* __restrict__ Tb)
{
    const int tid = threadIdx.x;
    if (blockIdx.x < POOL_BLOCKS) {
        // ----- pool path -----
        const int b = blockIdx.x;
        __shared__ int sid[SEQ];
        __shared__ float red[320];
        for (int s = tid; s < SEQ; s += 320) sid[s] = ids[s * B_ + b];
        __syncthreads();
        const int d = tid;
        float a0 = 0.f, a1 = 0.f, a2 = 0.f, a3 = 0.f;
        if (d < D_) {
            #pragma unroll 2
            for (int s = 0; s < SEQ; s += 4) {
                a0 += W[(size_t)sid[s]     * D_ + d];
                a1 += W[(size_t)sid[s + 1] * D_ + d];
                a2 += W[(size_t)sid[s + 2] * D_ + d];
                a3 += W[(size_t)sid[s + 3] * D_ + d];
            }
        }
        float xv = ((a0 + a1) + (a2 + a3)) * (1.0f / SEQ);
        red[d] = (d < D_) ? xv * xv : 0.f;
        __syncthreads();
        if (tid < 64) {
            float s = 0.f;
            #pragma unroll
            for (int i = 0; i < 5; ++i) s += red[tid + i * 64];
            #pragma unroll
            for (int m = 32; m >= 1; m >>= 1) s += __shfl_xor(s, m, 64);
            if (tid == 0) rxn[b] = 1.0f / fmaxf(sqrtf(s), EPS);
        }
        if (d < D_) {
            x[(size_t)b * D_ + d] = xv;
            xh[(size_t)b * DP + d] = f2bf(xv);
        } else {
            xh[(size_t)b * DP + d] = 0;
        }
    } else {
        // ----- tnorm/convert path -----
        const int n = (blockIdx.x - POOL_BLOCKS) * 5 + (tid >> 6);
        const int lane = tid & 63;
        if (n >= NTP) return;
        ushort4* tb = (ushort4*)(Tb + (size_t)n * DP);   // 80 ushort4/row
        if (n >= NT) {
            ushort4 z = {0, 0, 0, 0};
            tb[lane] = z;
            if (lane < 16) tb[64 + lane] = z;
            if (lane == 0) rtn[n] = 0.f;
            return;
        }
        const float4* Tr = (const float4*)(T + (size_t)n * D_);
        float4 v = Tr[lane];
        float s = v.x * v.x + v.y * v.y + v.z * v.z + v.w * v.w;
        ushort4 o; o.x = f2bf(v.x); o.y = f2bf(v.y); o.z = f2bf(v.z); o.w = f2bf(v.w);
        tb[lane] = o;
        if (lane < 16) {
            if (lane < 11) {
                float4 w = Tr[64 + lane];
                s += w.x * w.x + w.y * w.y + w.z * w.z + w.w * w.w;
                ushort4 p; p.x = f2bf(w.x); p.y = f2bf(w.y); p.z = f2bf(w.z); p.w = f2bf(w.w);
                tb[64 + lane] = p;
            } else {
                ushort4 z = {0, 0, 0, 0};
                tb[64 + lane] = z;
            }
        }
        #pragma unroll
        for (int m = 32; m >= 1; m >>= 1) s += __shfl_xor(s, m, 64);
        if (lane == 0) rtn[n] = 1.0f / fmaxf(sqrtf(s), EPS);
    }
}

// ---------------------------------------------------------------------------
// K2: hh bf16 GEMM, 256x128 tile, 512 threads (8 waves of 64x64 sub-tiles),
// BK=64, global_load_lds width-16 with xor-swizzled global chunk pick.
// XCD swizzle: all 4 M-blocks of a strip share g%8 (one XCD -> L2 reuse).
// Epilogue: per-(row,strip) max sim key -> blockmax.
// ---------------------------------------------------------------------------
__global__ __launch_bounds__(512, 6) void gemm_hh_kernel(
    const unsigned short* __restrict__ Ah, const unsigned short* __restrict__ Tb,
    const float* __restrict__ rxn, const float* __restrict__ rtn,
    u32* __restrict__ blockmax)
{
    __shared__ unsigned short sA[BM * BK];   // 32 KB
    __shared__ unsigned short sB[BN * BK];   // 16 KB
    __shared__ u32 sBest[BM];

    const int tid = threadIdx.x;
    const int g = blockIdx.x;
    const int k8 = g & 7;
    const int h = g >> 3;                 // 0..391
    const int bMi = h & 3;                // M-tile (4 of them)
    const int strip = ((h >> 2) << 3) | k8;   // same g%8 for a strip's 4 blocks

    const int lane = tid & 63, wid = tid >> 6;
    const int wm = wid >> 1, wn = wid & 1;    // 4 x 2 waves over 256 x 128
    const int quad = lane >> 4, l15 = lane & 15;

    // staging: call j -> chunk L = (j*8+wid)*64+lane at LDS byte L*16.
    // pick GLOBAL chunk (r=L>>3, c=(L&7)^(r&7)) so LDS is xor-swizzled.
    const unsigned short* pA[4];
    int laA[4];
    #pragma unroll
    for (int j = 0; j < 4; ++j) {
        int L = (j * 8 + wid) * 64 + lane;
        int r = L >> 3, c = (L & 7) ^ (r & 7);
        laA[j] = (j * 8 + wid) * 1024;
        pA[j] = Ah + (size_t)(bMi * BM + r) * DP + c * 8;
    }
    const unsigned short* pB[2];
    int laB[2];
    #pragma unroll
    for (int j = 0; j < 2; ++j) {
        int L = (j * 8 + wid) * 64 + lane;
        int r = L >> 3, c = (L & 7) ^ (r & 7);
        laB[j] = (j * 8 + wid) * 1024;
        pB[j] = Tb + (size_t)(strip * BN + r) * DP + c * 8;
    }

    f32x4 acc[4][4] = {};

    for (int kp = 0; kp < DP; kp += BK) {
        #pragma unroll
        for (int j = 0; j < 4; ++j)
            gload_lds16(pA[j] + kp, (char*)sA + laA[j]);
        #pragma unroll
        for (int j = 0; j < 2; ++j)
            gload_lds16(pB[j] + kp, (char*)sB + laB[j]);
        __syncthreads();

        #pragma unroll
        for (int s = 0; s < 2; ++s) {
            bf16x8 fa[4], fb[4];
            #pragma unroll
            for (int f = 0; f < 4; ++f) {
                int ar = wm * 64 + f * 16 + l15;
                int ac = (s * 4 + quad) ^ (ar & 7);
                fa[f] = *(const bf16x8*)&sA[ar * BK + ac * 8];
                int br = wn * 64 + f * 16 + l15;
                int bc = (s * 4 + quad) ^ (br & 7);
                fb[f] = *(const bf16x8*)&sB[br * BK + bc * 8];
            }
            #pragma unroll
            for (int fm = 0; fm < 4; ++fm)
                #pragma unroll
                for (int fn = 0; fn < 4; ++fn)
                    acc[fm][fn] = __builtin_amdgcn_mfma_f32_16x16x32_bf16(
                        fa[fm], fb[fn], acc[fm][fn], 0, 0, 0);
        }
        __syncthreads();
    }

    // ---- epilogue: per-row max sim key ----
    if (tid < BM) sBest[tid] = 0u;
    __syncthreads();
    float rt[4];
    const int gn0 = strip * BN + wn * 64 + l15;
    #pragma unroll
    for (int fn = 0; fn < 4; ++fn)
        rt[fn] = (gn0 + fn * 16 < NT) ? rtn[gn0 + fn * 16] : 0.f;
    #pragma unroll
    for (int fm = 0; fm < 4; ++fm) {
        #pragma unroll
        for (int r = 0; r < 4; ++r) {
            int rowl = wm * 64 + fm * 16 + quad * 4 + r;   // C row = quad*4+reg
            float rx = rxn[bMi * BM + rowl];
            u32 bk = 0u;
            #pragma unroll
            for (int fn = 0; fn < 4; ++fn) {
                float sim = acc[fm][fn][r] * rx * rt[fn];
                u32 k = simkey(sim);
                bk = (k > bk) ? k : bk;
            }
            #pragma unroll
            for (int m = 1; m < 16; m <<= 1) {
                u32 o = __shfl_xor(bk, m, 64);
                bk = (o > bk) ? o : bk;
            }
            if (l15 == 0) atomicMax(&sBest[rowl], bk);
        }
    }
    __syncthreads();
    if (tid < BM)
        blockmax[(size_t)(bMi * BM + tid) * NSTRIP + strip] = sBest[tid];
}

// ---------------------------------------------------------------------------
// K3 "finalize": per batch row -- threshold scan, collect qualifying strips,
// exact fp32 rescore of their 128 cols, pick winner, fp64 score + label.
// ---------------------------------------------------------------------------
__global__ __launch_bounds__(256) void finalize_kernel(
    const u32* __restrict__ blockmax, const float* __restrict__ x,
    const float* __restrict__ T, const float* __restrict__ rxn,
    const int* __restrict__ y_train, float* __restrict__ out)
{
    const int row = blockIdx.x;
    const int t = threadIdx.x;
    const int w = t >> 6, lane = t & 63;
    const u32* bmr = blockmax + (size_t)row * NSTRIP;

    __shared__ u32 wred[4];
    __shared__ float thr_s;
    __shared__ int qn_s;
    __shared__ int ql[128];
    __shared__ float4 xs4[75];
    __shared__ u64 wbest[4];
    __shared__ int widx_s;

    if (t == 0) qn_s = 0;
    u32 m = 0u;
    for (int j = t; j < NSTRIP; j += 256) { u32 e = bmr[j]; m = (e > m) ? e : m; }
    #pragma unroll
    for (int msk = 32; msk >= 1; msk >>= 1) {
        u32 o = __shfl_xor(m, msk, 64);
        m = (o > m) ? o : m;
    }
    if (lane == 0) wred[w] = m;
    __syncthreads();
    if (t == 0) {
        u32 gmx = wred[0];
        for (int i = 1; i < 4; ++i) gmx = (wred[i] > gmx) ? wred[i] : gmx;
        thr_s = keysim(gmx) - MARGIN;
    }
    __syncthreads();
    const float thr = thr_s;
    for (int j = t; j < NSTRIP; j += 256) {
        if (keysim(bmr[j]) >= thr) {
            int p = atomicAdd(&qn_s, 1);
            if (p < 128) ql[p] = j;
        }
    }
    if (t < 75) xs4[t] = *(const float4*)&x[(size_t)row * D_ + t * 4];
    __syncthreads();

    const float rx = rxn[row];
    int nq = qn_s; if (nq > 128) nq = 128;
    u64 best = 0ull;
    for (int q = 0; q < nq; ++q) {
        const int strip = ql[q];
        for (int cc = 0; cc < 32; ++cc) {
            int n = strip * BN + w * 32 + cc;
            if (n >= NT) continue;               // wave-uniform
            const float4* Tr = (const float4*)(T + (size_t)n * D_);
            float4 v = Tr[lane], xv = xs4[lane];
            float dot = v.x * xv.x + v.y * xv.y + v.z * xv.z + v.w * xv.w;
            float tt  = v.x * v.x + v.y * v.y + v.z * v.z + v.w * v.w;
            if (lane < 11) {
                float4 v2 = Tr[64 + lane], x2 = xs4[64 + lane];
                dot += v2.x * x2.x + v2.y * x2.y + v2.z * x2.z + v2.w * x2.w;
                tt  += v2.x * v2.x + v2.y * v2.y + v2.z * v2.z + v2.w * v2.w;
            }
            #pragma unroll
            for (int msk = 32; msk >= 1; msk >>= 1) {
                dot += __shfl_xor(dot, msk, 64);
                tt  += __shfl_xor(tt, msk, 64);
            }
            float sim = dot * rx / fmaxf(sqrtf(tt), EPS);
            u64 pk = ((u64)simkey(sim) << 32) | (u32)(~n);
            best = (pk > best) ? pk : best;
        }
    }
    if (lane == 0) wbest[w] = best;
    __syncthreads();
    if (t == 0) {
        u64 gb = wbest[0];
        for (int i = 1; i < 4; ++i) gb = (wbest[i] > gb) ? wbest[i] : gb;
        int idx = (int)(~(u32)gb);
        if (idx < 0 || idx >= NT) idx = 0;
        widx_s = idx;
    }
    __syncthreads();
    if (w == 0) {
        const int idx = widx_s;
        double dot = 0.0, nx = 0.0, nt = 0.0;
        for (int d = lane; d < D_; d += 64) {
            double xv = (double)x[(size_t)row * D_ + d];
            double tv = (double)T[(size_t)idx * D_ + d];
            dot += xv * tv; nx += xv * xv; nt += tv * tv;
        }
        #pragma unroll
        for (int msk = 32; msk >= 1; msk >>= 1) {
            dot += __shfl_xor(dot, msk, 64);
            nx  += __shfl_xor(nx, msk, 64);
            nt  += __shfl_xor(nt, msk, 64);
        }
        if (lane == 0) {
            double score = dot / (fmax(sqrt(nx), (double)EPS) * fmax(sqrt(nt), (double)EPS));
            out[row]      = (float)y_train[idx];
            out[B_ + row] = (float)score;
        }
    }
}

// ---------------------------------------------------------------------------
extern "C" void kernel_launch(void* const* d_in, const int* in_sizes, int n_in,
                              void* d_out, int out_size, void* d_ws, size_t ws_size,
                              hipStream_t stream)
{
    const int*   ids = (const int*)d_in[0];
    const float* W   = (const float*)d_in[1];
    const float* T   = (const float*)d_in[2];
    const int*   y   = (const int*)d_in[3];

    char* ws = (char*)d_ws;
    size_t off = 0;
    float* x           = (float*)(ws + off);          off += (size_t)B_ * D_ * 4;        // 1,228,800
    unsigned short* xh = (unsigned short*)(ws + off); off += (size_t)B_ * DP * 2;        //   655,360
    float* rxn         = (float*)(ws + off);          off += (size_t)B_ * 4;             //     4,096
    float* rtn         = (float*)(ws + off);          off += (size_t)NTP * 4;            //   401,408
    unsigned short* Tb = (unsigned short*)(ws + off); off += (size_t)NTP * DP * 2;       // 64,225,280
    u32* blockmax      = (u32*)(ws + off);            off += (size_t)B_ * NSTRIP * 4;    //  3,211,264
                                                                                         // total ~70 MB
    prep_kernel<<<POOL_BLOCKS + TN_BLOCKS, 320, 0, stream>>>(ids, W, T, x, xh, rxn, rtn, Tb);
    gemm_hh_kernel<<<NSTRIP * 4, 512, 0, stream>>>(xh, Tb, rxn, rtn, blockmax);
    finalize_kernel<<<B_, 256, 0, stream>>>(blockmax, x, T, rxn, y, (float*)d_out);
}

// Round 5
// 472.651 us; speedup vs baseline: 1.7074x; 1.7074x over previous
//
#include <hip/hip_runtime.h>
#include <hip/hip_bf16.h>
#include <stdint.h>

#define EPS 1e-8f

typedef __attribute__((ext_vector_type(8))) short bf16x8;
typedef __attribute__((ext_vector_type(4))) float f32x4;
typedef unsigned long long u64;
typedef unsigned int u32;

constexpr int SEQ = 200;
constexpr int B_  = 1024;    // batch
constexpr int D_  = 300;     // embedding dim
constexpr int DP  = 320;     // K padded
constexpr int NT  = 100000;  // train rows
constexpr int BM = 128, BN = 128, BK = 64;
constexpr int NSTRIP = 784;            // N strips (128 wide), multiple of 8
constexpr int NTP = NSTRIP * BN;       // 100352 padded rows
constexpr int POOL_BLOCKS = B_;        // 1024
constexpr int TN_BLOCKS = (NTP + 4) / 5;   // 20071 (5 rows/block)
#define MARGIN 2e-3f

__device__ __forceinline__ unsigned short f2bf(float f) {   // RNE
    u32 b = __float_as_uint(f);
    return (unsigned short)((b + 0x7fffu + ((b >> 16) & 1u)) >> 16);
}
__device__ __forceinline__ u32 simkey(float s) {            // order-preserving
    u32 b = __float_as_uint(s);
    return (b & 0x80000000u) ? ~b : (b | 0x80000000u);
}
__device__ __forceinline__ float keysim(u32 k) {
    u32 b = (k & 0x80000000u) ? (k & 0x7fffffffu) : ~k;
    return __uint_as_float(b);
}
__device__ __forceinline__ void gload_lds16(const void* g, void* l) {
    __builtin_amdgcn_global_load_lds(
        (const __attribute__((address_space(1))) unsigned int*)g,
        (__attribute__((address_space(3))) unsigned int*)l, 16, 0, 0);
}

// ---------------------------------------------------------------------------
// K1 "prep": fused pool (blocks 0..1023) + tnorm/convert (rest).
// Pool: writes x fp32, xh = bf16(x/||x||) (cols 300..319 = 0), rxn.
// Tnorm: 5 rows/block, writes Tb = bf16(t/||t||) (rows/cols zero-padded).
// ---------------------------------------------------------------------------
__global__ __launch_bounds__(320) void prep_kernel(
    const int* __restrict__ ids, const float* __restrict__ W,
    const float* __restrict__ T,
    float* __restrict__ x, unsigned short* __restrict__ xh,
    float* __restrict__ rxn, unsigned short* __restrict__ Tb)
{
    const int tid = threadIdx.x;
    if (blockIdx.x < POOL_BLOCKS) {
        // ----- pool path -----
        const int b = blockIdx.x;
        __shared__ int sid[SEQ];
        __shared__ float red[320];
        __shared__ float rns_s;
        for (int s = tid; s < SEQ; s += 320) sid[s] = ids[s * B_ + b];
        __syncthreads();
        const int d = tid;
        float a0 = 0.f, a1 = 0.f, a2 = 0.f, a3 = 0.f;
        if (d < D_) {
            #pragma unroll 2
            for (int s = 0; s < SEQ; s += 4) {
                a0 += W[(size_t)sid[s]     * D_ + d];
                a1 += W[(size_t)sid[s + 1] * D_ + d];
                a2 += W[(size_t)sid[s + 2] * D_ + d];
                a3 += W[(size_t)sid[s + 3] * D_ + d];
            }
        }
        float xv = ((a0 + a1) + (a2 + a3)) * (1.0f / SEQ);
        red[d] = (d < D_) ? xv * xv : 0.f;
        __syncthreads();
        if (tid < 64) {
            float s = 0.f;
            #pragma unroll
            for (int i = 0; i < 5; ++i) s += red[tid + i * 64];
            #pragma unroll
            for (int m = 32; m >= 1; m >>= 1) s += __shfl_xor(s, m, 64);
            if (tid == 0) {
                float r = 1.0f / fmaxf(sqrtf(s), EPS);
                rxn[b] = r;
                rns_s = r;
            }
        }
        __syncthreads();
        const float rns = rns_s;
        if (d < D_) {
            x[(size_t)b * D_ + d] = xv;
            xh[(size_t)b * DP + d] = f2bf(xv * rns);
        } else {
            xh[(size_t)b * DP + d] = 0;
        }
    } else {
        // ----- tnorm/convert path: normalized bf16 rows -----
        const int n = (blockIdx.x - POOL_BLOCKS) * 5 + (tid >> 6);
        const int lane = tid & 63;
        if (n >= NTP) return;
        ushort4* tb = (ushort4*)(Tb + (size_t)n * DP);   // 80 ushort4/row
        if (n >= NT) {
            ushort4 z = {0, 0, 0, 0};
            tb[lane] = z;
            if (lane < 16) tb[64 + lane] = z;
            return;
        }
        const float4* Tr = (const float4*)(T + (size_t)n * D_);
        float4 v = Tr[lane];
        float s = v.x * v.x + v.y * v.y + v.z * v.z + v.w * v.w;
        float4 w2 = make_float4(0.f, 0.f, 0.f, 0.f);
        if (lane < 11) {
            w2 = Tr[64 + lane];
            s += w2.x * w2.x + w2.y * w2.y + w2.z * w2.z + w2.w * w2.w;
        }
        #pragma unroll
        for (int m = 32; m >= 1; m >>= 1) s += __shfl_xor(s, m, 64);
        const float rns = 1.0f / fmaxf(sqrtf(s), EPS);
        ushort4 o;
        o.x = f2bf(v.x * rns); o.y = f2bf(v.y * rns);
        o.z = f2bf(v.z * rns); o.w = f2bf(v.w * rns);
        tb[lane] = o;
        if (lane < 16) {
            ushort4 p = {0, 0, 0, 0};
            if (lane < 11) {
                p.x = f2bf(w2.x * rns); p.y = f2bf(w2.y * rns);
                p.z = f2bf(w2.z * rns); p.w = f2bf(w2.w * rns);
            }
            tb[64 + lane] = p;
        }
    }
}

// ---------------------------------------------------------------------------
// K2: hh bf16 GEMM on normalized operands (acc IS the sim). 128x128 tile,
// 256 threads, BK=64, global_load_lds width-16, xor-swizzled global chunk
// pick -> swizzled LDS. XCD swizzle: a strip's 8 M-blocks share g%8.
// Epilogue: per-(row,strip) max sim key -> blockmax.
// ---------------------------------------------------------------------------
__global__ __launch_bounds__(256, 3) void gemm_hh_kernel(
    const unsigned short* __restrict__ Ah, const unsigned short* __restrict__ Tb,
    u32* __restrict__ blockmax)
{
    __shared__ unsigned short sA[BM * BK];   // 16 KB
    __shared__ unsigned short sB[BN * BK];   // 16 KB
    __shared__ u32 sBest[BM];

    const int tid = threadIdx.x;
    const int g = blockIdx.x;
    const int k8 = g & 7;
    const int t = g >> 3;
    const int bMi = t & 7;                       // M-tile
    const int strip = ((t >> 3) << 3) | k8;      // same XCD for a strip's tiles

    const int lane = tid & 63, wid = tid >> 6;
    const int wm = wid >> 1, wn = wid & 1;
    const int quad = lane >> 4, l15 = lane & 15;

    // staging: call j -> chunk L=(j*4+wid)*64+lane at LDS byte L*16; pick
    // GLOBAL chunk (r=L>>3, c=(L&7)^(r&7)) so LDS ends up xor-swizzled.
    const unsigned short* pA[4];
    const unsigned short* pB[4];
    int ldsoff[4];
    #pragma unroll
    for (int j = 0; j < 4; ++j) {
        int L = (j * 4 + wid) * 64 + lane;
        int r = L >> 3;
        int c = (L & 7) ^ (r & 7);
        ldsoff[j] = (j * 4 + wid) * 1024;
        pA[j] = Ah + (size_t)(bMi * BM + r) * DP + c * 8;
        pB[j] = Tb + (size_t)(strip * BN + r) * DP + c * 8;
    }

    f32x4 acc[4][4] = {};

    for (int kp = 0; kp < DP; kp += BK) {
        #pragma unroll
        for (int j = 0; j < 4; ++j)
            gload_lds16(pA[j] + kp, (char*)sA + ldsoff[j]);
        #pragma unroll
        for (int j = 0; j < 4; ++j)
            gload_lds16(pB[j] + kp, (char*)sB + ldsoff[j]);
        __syncthreads();

        #pragma unroll
        for (int s = 0; s < 2; ++s) {
            bf16x8 fa[4], fb[4];
            #pragma unroll
            for (int f = 0; f < 4; ++f) {
                int ar = wm * 64 + f * 16 + l15;
                int ac = (s * 4 + quad) ^ (ar & 7);
                fa[f] = *(const bf16x8*)&sA[ar * BK + ac * 8];
                int br = wn * 64 + f * 16 + l15;
                int bc = (s * 4 + quad) ^ (br & 7);
                fb[f] = *(const bf16x8*)&sB[br * BK + bc * 8];
            }
            #pragma unroll
            for (int fm = 0; fm < 4; ++fm)
                #pragma unroll
                for (int fn = 0; fn < 4; ++fn)
                    acc[fm][fn] = __builtin_amdgcn_mfma_f32_16x16x32_bf16(
                        fa[fm], fb[fn], acc[fm][fn], 0, 0, 0);
        }
        __syncthreads();
    }

    // ---- epilogue: per-row max sim key (acc is already the cosine) ----
    if (tid < BM) sBest[tid] = 0u;
    __syncthreads();
    #pragma unroll
    for (int fm = 0; fm < 4; ++fm) {
        #pragma unroll
        for (int r = 0; r < 4; ++r) {
            int rowl = wm * 64 + fm * 16 + quad * 4 + r;   // C row = quad*4+reg
            u32 bk = 0u;
            #pragma unroll
            for (int fn = 0; fn < 4; ++fn) {
                u32 k = simkey(acc[fm][fn][r]);
                bk = (k > bk) ? k : bk;
            }
            #pragma unroll
            for (int m = 1; m < 16; m <<= 1) {
                u32 o = __shfl_xor(bk, m, 64);
                bk = (o > bk) ? o : bk;
            }
            if (l15 == 0) atomicMax(&sBest[rowl], bk);
        }
    }
    __syncthreads();
    if (tid < BM)
        blockmax[(size_t)(bMi * BM + tid) * NSTRIP + strip] = sBest[tid];
}

// ---------------------------------------------------------------------------
// K3 "finalize": per batch row -- threshold scan, collect qualifying strips,
// exact fp32 rescore of their 128 cols, pick winner, fp64 score + label.
// ---------------------------------------------------------------------------
__global__ __launch_bounds__(256) void finalize_kernel(
    const u32* __restrict__ blockmax, const float* __restrict__ x,
    const float* __restrict__ T, const float* __restrict__ rxn,
    const int* __restrict__ y_train, float* __restrict__ out)
{
    const int row = blockIdx.x;
    const int t = threadIdx.x;
    const int w = t >> 6, lane = t & 63;
    const u32* bmr = blockmax + (size_t)row * NSTRIP;

    __shared__ u32 wred[4];
    __shared__ float thr_s;
    __shared__ int qn_s;
    __shared__ int ql[128];
    __shared__ float4 xs4[75];
    __shared__ u64 wbest[4];
    __shared__ int widx_s;

    if (t == 0) qn_s = 0;
    u32 m = 0u;
    for (int j = t; j < NSTRIP; j += 256) { u32 e = bmr[j]; m = (e > m) ? e : m; }
    #pragma unroll
    for (int msk = 32; msk >= 1; msk >>= 1) {
        u32 o = __shfl_xor(m, msk, 64);
        m = (o > m) ? o : m;
    }
    if (lane == 0) wred[w] = m;
    __syncthreads();
    if (t == 0) {
        u32 gmx = wred[0];
        for (int i = 1; i < 4; ++i) gmx = (wred[i] > gmx) ? wred[i] : gmx;
        thr_s = keysim(gmx) - MARGIN;
    }
    __syncthreads();
    const float thr = thr_s;
    for (int j = t; j < NSTRIP; j += 256) {
        if (keysim(bmr[j]) >= thr) {
            int p = atomicAdd(&qn_s, 1);
            if (p < 128) ql[p] = j;
        }
    }
    if (t < 75) xs4[t] = *(const float4*)&x[(size_t)row * D_ + t * 4];
    __syncthreads();

    const float rx = rxn[row];
    int nq = qn_s; if (nq > 128) nq = 128;
    u64 best = 0ull;
    for (int q = 0; q < nq; ++q) {
        const int strip = ql[q];
        for (int cc = 0; cc < 32; ++cc) {
            int n = strip * BN + w * 32 + cc;
            if (n >= NT) continue;               // wave-uniform
            const float4* Tr = (const float4*)(T + (size_t)n * D_);
            float4 v = Tr[lane], xv = xs4[lane];
            float dot = v.x * xv.x + v.y * xv.y + v.z * xv.z + v.w * xv.w;
            float tt  = v.x * v.x + v.y * v.y + v.z * v.z + v.w * v.w;
            if (lane < 11) {
                float4 v2 = Tr[64 + lane], x2 = xs4[64 + lane];
                dot += v2.x * x2.x + v2.y * x2.y + v2.z * x2.z + v2.w * x2.w;
                tt  += v2.x * v2.x + v2.y * v2.y + v2.z * v2.z + v2.w * v2.w;
            }
            #pragma unroll
            for (int msk = 32; msk >= 1; msk >>= 1) {
                dot += __shfl_xor(dot, msk, 64);
                tt  += __shfl_xor(tt, msk, 64);
            }
            float sim = dot * rx / fmaxf(sqrtf(tt), EPS);
            u64 pk = ((u64)simkey(sim) << 32) | (u32)(~n);
            best = (pk > best) ? pk : best;
        }
    }
    if (lane == 0) wbest[w] = best;
    __syncthreads();
    if (t == 0) {
        u64 gb = wbest[0];
        for (int i = 1; i < 4; ++i) gb = (wbest[i] > gb) ? wbest[i] : gb;
        int idx = (int)(~(u32)gb);
        if (idx < 0 || idx >= NT) idx = 0;
        widx_s = idx;
    }
    __syncthreads();
    if (w == 0) {
        const int idx = widx_s;
        double dot = 0.0, nx = 0.0, nt = 0.0;
        for (int d = lane; d < D_; d += 64) {
            double xv = (double)x[(size_t)row * D_ + d];
            double tv = (double)T[(size_t)idx * D_ + d];
            dot += xv * tv; nx += xv * xv; nt += tv * tv;
        }
        #pragma unroll
        for (int msk = 32; msk >= 1; msk >>= 1) {
            dot += __shfl_xor(dot, msk, 64);
            nx  += __shfl_xor(nx, msk, 64);
            nt  += __shfl_xor(nt, msk, 64);
        }
        if (lane == 0) {
            double score = dot / (fmax(sqrt(nx), (double)EPS) * fmax(sqrt(nt), (double)EPS));
            out[row]      = (float)y_train[idx];
            out[B_ + row] = (float)score;
        }
    }
}

// ---------------------------------------------------------------------------
extern "C" void kernel_launch(void* const* d_in, const int* in_sizes, int n_in,
                              void* d_out, int out_size, void* d_ws, size_t ws_size,
                              hipStream_t stream)
{
    const int*   ids = (const int*)d_in[0];
    const float* W   = (const float*)d_in[1];
    const float* T   = (const float*)d_in[2];
    const int*   y   = (const int*)d_in[3];

    char* ws = (char*)d_ws;
    size_t off = 0;
    float* x           = (float*)(ws + off);          off += (size_t)B_ * D_ * 4;        // 1,228,800
    unsigned short* xh = (unsigned short*)(ws + off); off += (size_t)B_ * DP * 2;        //   655,360
    float* rxn         = (float*)(ws + off);          off += (size_t)B_ * 4;             //     4,096
    unsigned short* Tb = (unsigned short*)(ws + off); off += (size_t)NTP * DP * 2;       // 64,225,280
    u32* blockmax      = (u32*)(ws + off);            off += (size_t)B_ * NSTRIP * 4;    //  3,211,264
                                                                                         // total ~69 MB
    prep_kernel<<<POOL_BLOCKS + TN_BLOCKS, 320, 0, stream>>>(ids, W, T, x, xh, rxn, Tb);
    gemm_hh_kernel<<<NSTRIP * 8, 256, 0, stream>>>(xh, Tb, blockmax);
    finalize_kernel<<<B_, 256, 0, stream>>>(blockmax, x, T, rxn, y, (float*)d_out);
}

// Round 6
// 373.636 us; speedup vs baseline: 2.1599x; 1.2650x over previous
//
#include <hip/hip_runtime.h>
#include <hip/hip_bf16.h>
#include <stdint.h>

#define EPS 1e-8f

typedef __attribute__((ext_vector_type(8))) short bf16x8;
typedef __attribute__((ext_vector_type(4))) float f32x4;
typedef unsigned long long u64;
typedef unsigned int u32;

constexpr int SEQ = 200;
constexpr int B_  = 1024;    // batch
constexpr int D_  = 300;     // embedding dim
constexpr int DP  = 320;     // K padded
constexpr int NT  = 100000;  // train rows
constexpr int BM = 128, BN = 128, BK = 64;
constexpr int NSTRIP = 784;            // N strips (128 wide), multiple of 8
constexpr int NTP = NSTRIP * BN;       // 100352 padded rows
constexpr int POOL_BLOCKS = B_;        // 1024
constexpr int TN_BLOCKS = (NTP + 9) / 10;  // 10036 (10 rows/block @ 640 thr)
constexpr int CAND_MAX = 8192;
#define MARGIN 2e-3f

__device__ __forceinline__ unsigned short f2bf(float f) {   // RNE
    u32 b = __float_as_uint(f);
    return (unsigned short)((b + 0x7fffu + ((b >> 16) & 1u)) >> 16);
}
__device__ __forceinline__ u32 simkey(float s) {            // order-preserving
    u32 b = __float_as_uint(s);
    return (b & 0x80000000u) ? ~b : (b | 0x80000000u);
}
__device__ __forceinline__ float keysim(u32 k) {
    u32 b = (k & 0x80000000u) ? (k & 0x7fffffffu) : ~k;
    return __uint_as_float(b);
}
__device__ __forceinline__ void gload_lds16(const void* g, void* l) {
    __builtin_amdgcn_global_load_lds(
        (const __attribute__((address_space(1))) unsigned int*)g,
        (__attribute__((address_space(3))) unsigned int*)l, 16, 0, 0);
}

// ---------------------------------------------------------------------------
// K1 "prep": fused pool (blocks 0..1023, 640 thr: seq halves x 2 chains)
// + tnorm/convert (10 rows/block). Pool writes x fp32, xh = bf16(x/||x||)
// (cols 300..319 = 0), rxn. Tnorm writes Tb = bf16(t/||t||) (zero-padded).
// Block 0 also zeroes the candidate counter.
// ---------------------------------------------------------------------------
__global__ __launch_bounds__(640) void prep_kernel(
    const int* __restrict__ ids, const float* __restrict__ W,
    const float* __restrict__ T,
    float* __restrict__ x, unsigned short* __restrict__ xh,
    float* __restrict__ rxn, unsigned short* __restrict__ Tb,
    u32* __restrict__ count)
{
    const int tid = threadIdx.x;
    if (blockIdx.x < POOL_BLOCKS) {
        // ----- pool path -----
        const int b = blockIdx.x;
        if (b == 0 && tid == 0) *count = 0;
        __shared__ int sid[SEQ];
        __shared__ float part[640];
        __shared__ float rns_s;
        for (int s = tid; s < SEQ; s += 640) sid[s] = ids[s * B_ + b];
        __syncthreads();
        const int half = (tid >= 320) ? 1 : 0;
        const int d = tid - half * 320;
        float a0 = 0.f, a1 = 0.f;
        if (d < D_) {
            const int s0 = half * (SEQ / 2);
            #pragma unroll 2
            for (int s = 0; s < SEQ / 2; s += 2) {
                a0 += W[(size_t)sid[s0 + s]     * D_ + d];
                a1 += W[(size_t)sid[s0 + s + 1] * D_ + d];
            }
        }
        part[tid] = a0 + a1;
        __syncthreads();
        float xv = 0.f;
        if (tid < 320) xv = (part[tid] + part[tid + 320]) * (1.0f / SEQ);
        __syncthreads();
        if (tid < 320) part[tid] = (tid < D_) ? xv * xv : 0.f;
        __syncthreads();
        if (tid < 64) {
            float s = 0.f;
            #pragma unroll
            for (int i = 0; i < 5; ++i) s += part[tid + i * 64];
            #pragma unroll
            for (int m = 32; m >= 1; m >>= 1) s += __shfl_xor(s, m, 64);
            if (tid == 0) {
                float r = 1.0f / fmaxf(sqrtf(s), EPS);
                rxn[b] = r;
                rns_s = r;
            }
        }
        __syncthreads();
        const float rns = rns_s;
        if (tid < 320) {
            if (tid < D_) {
                x[(size_t)b * D_ + tid] = xv;
                xh[(size_t)b * DP + tid] = f2bf(xv * rns);
            } else {
                xh[(size_t)b * DP + tid] = 0;
            }
        }
    } else {
        // ----- tnorm/convert path: normalized bf16 rows -----
        const int n = (blockIdx.x - POOL_BLOCKS) * 10 + (tid >> 6);
        const int lane = tid & 63;
        if (n >= NTP) return;
        ushort4* tb = (ushort4*)(Tb + (size_t)n * DP);   // 80 ushort4/row
        if (n >= NT) {
            ushort4 z = {0, 0, 0, 0};
            tb[lane] = z;
            if (lane < 16) tb[64 + lane] = z;
            return;
        }
        const float4* Tr = (const float4*)(T + (size_t)n * D_);
        float4 v = Tr[lane];
        float s = v.x * v.x + v.y * v.y + v.z * v.z + v.w * v.w;
        float4 w2 = make_float4(0.f, 0.f, 0.f, 0.f);
        if (lane < 11) {
            w2 = Tr[64 + lane];
            s += w2.x * w2.x + w2.y * w2.y + w2.z * w2.z + w2.w * w2.w;
        }
        #pragma unroll
        for (int m = 32; m >= 1; m >>= 1) s += __shfl_xor(s, m, 64);
        const float rns = 1.0f / fmaxf(sqrtf(s), EPS);
        ushort4 o;
        o.x = f2bf(v.x * rns); o.y = f2bf(v.y * rns);
        o.z = f2bf(v.z * rns); o.w = f2bf(v.w * rns);
        tb[lane] = o;
        if (lane < 16) {
            ushort4 p = {0, 0, 0, 0};
            if (lane < 11) {
                p.x = f2bf(w2.x * rns); p.y = f2bf(w2.y * rns);
                p.z = f2bf(w2.z * rns); p.w = f2bf(w2.w * rns);
            }
            tb[64 + lane] = p;
        }
    }
}

// ---------------------------------------------------------------------------
// K2: hh bf16 GEMM on normalized operands (acc IS the sim). 128x128 tile,
// 256 threads, BK=64, global_load_lds width-16, xor-swizzled global chunk
// pick -> swizzled LDS. XCD swizzle: a strip's 8 M-blocks share g%8.
// Epilogue: per-(row,strip) max sim key -> blockmax.
// ---------------------------------------------------------------------------
__global__ __launch_bounds__(256, 3) void gemm_hh_kernel(
    const unsigned short* __restrict__ Ah, const unsigned short* __restrict__ Tb,
    u32* __restrict__ blockmax)
{
    __shared__ unsigned short sA[BM * BK];   // 16 KB
    __shared__ unsigned short sB[BN * BK];   // 16 KB
    __shared__ u32 sBest[BM];

    const int tid = threadIdx.x;
    const int g = blockIdx.x;
    const int k8 = g & 7;
    const int t = g >> 3;
    const int bMi = t & 7;                       // M-tile
    const int strip = ((t >> 3) << 3) | k8;      // same XCD for a strip's tiles

    const int lane = tid & 63, wid = tid >> 6;
    const int wm = wid >> 1, wn = wid & 1;
    const int quad = lane >> 4, l15 = lane & 15;

    const unsigned short* pA[4];
    const unsigned short* pB[4];
    int ldsoff[4];
    #pragma unroll
    for (int j = 0; j < 4; ++j) {
        int L = (j * 4 + wid) * 64 + lane;
        int r = L >> 3;
        int c = (L & 7) ^ (r & 7);
        ldsoff[j] = (j * 4 + wid) * 1024;
        pA[j] = Ah + (size_t)(bMi * BM + r) * DP + c * 8;
        pB[j] = Tb + (size_t)(strip * BN + r) * DP + c * 8;
    }

    f32x4 acc[4][4] = {};

    for (int kp = 0; kp < DP; kp += BK) {
        #pragma unroll
        for (int j = 0; j < 4; ++j)
            gload_lds16(pA[j] + kp, (char*)sA + ldsoff[j]);
        #pragma unroll
        for (int j = 0; j < 4; ++j)
            gload_lds16(pB[j] + kp, (char*)sB + ldsoff[j]);
        __syncthreads();

        #pragma unroll
        for (int s = 0; s < 2; ++s) {
            bf16x8 fa[4], fb[4];
            #pragma unroll
            for (int f = 0; f < 4; ++f) {
                int ar = wm * 64 + f * 16 + l15;
                int ac = (s * 4 + quad) ^ (ar & 7);
                fa[f] = *(const bf16x8*)&sA[ar * BK + ac * 8];
                int br = wn * 64 + f * 16 + l15;
                int bc = (s * 4 + quad) ^ (br & 7);
                fb[f] = *(const bf16x8*)&sB[br * BK + bc * 8];
            }
            #pragma unroll
            for (int fm = 0; fm < 4; ++fm)
                #pragma unroll
                for (int fn = 0; fn < 4; ++fn)
                    acc[fm][fn] = __builtin_amdgcn_mfma_f32_16x16x32_bf16(
                        fa[fm], fb[fn], acc[fm][fn], 0, 0, 0);
        }
        __syncthreads();
    }

    if (tid < BM) sBest[tid] = 0u;
    __syncthreads();
    #pragma unroll
    for (int fm = 0; fm < 4; ++fm) {
        #pragma unroll
        for (int r = 0; r < 4; ++r) {
            int rowl = wm * 64 + fm * 16 + quad * 4 + r;   // C row = quad*4+reg
            u32 bk = 0u;
            #pragma unroll
            for (int fn = 0; fn < 4; ++fn) {
                u32 k = simkey(acc[fm][fn][r]);
                bk = (k > bk) ? k : bk;
            }
            #pragma unroll
            for (int m = 1; m < 16; m <<= 1) {
                u32 o = __shfl_xor(bk, m, 64);
                bk = (o > bk) ? o : bk;
            }
            if (l15 == 0) atomicMax(&sBest[rowl], bk);
        }
    }
    __syncthreads();
    if (tid < BM)
        blockmax[(size_t)(bMi * BM + tid) * NSTRIP + strip] = sBest[tid];
}

// ---------------------------------------------------------------------------
// K3 "scan": per row, threshold = max(blockmax) - MARGIN; emit qualifying
// (row,strip) candidates to global list; zero winner[row].
// ---------------------------------------------------------------------------
__global__ __launch_bounds__(256) void scan_kernel(
    const u32* __restrict__ blockmax, u32* __restrict__ cand,
    u32* __restrict__ count, u64* __restrict__ winner)
{
    const int row = blockIdx.x;
    const int t = threadIdx.x;
    const int w = t >> 6, lane = t & 63;
    const u32* bmr = blockmax + (size_t)row * NSTRIP;

    __shared__ u32 wred[4];
    __shared__ float thr_s;
    if (t == 0) winner[row] = 0ull;
    u32 m = 0u;
    for (int j = t; j < NSTRIP; j += 256) { u32 e = bmr[j]; m = (e > m) ? e : m; }
    #pragma unroll
    for (int msk = 32; msk >= 1; msk >>= 1) {
        u32 o = __shfl_xor(m, msk, 64);
        m = (o > m) ? o : m;
    }
    if (lane == 0) wred[w] = m;
    __syncthreads();
    if (t == 0) {
        u32 gmx = wred[0];
        for (int i = 1; i < 4; ++i) gmx = (wred[i] > gmx) ? wred[i] : gmx;
        thr_s = keysim(gmx) - MARGIN;
    }
    __syncthreads();
    const float thr = thr_s;
    for (int j = t; j < NSTRIP; j += 256) {
        if (keysim(bmr[j]) >= thr) {
            u32 p = atomicAdd(count, 1u);
            if (p < CAND_MAX) cand[p] = ((u32)row << 10) | (u32)j;
        }
    }
}

// ---------------------------------------------------------------------------
// K4 "rescore": one block per candidate (row,strip). Each wave processes 16
// columns concurrently (4 lanes/col), exact fp32 dot + ||t||; atomicMax
// winner[row] with packed (key | ~idx).
// ---------------------------------------------------------------------------
__global__ __launch_bounds__(256) void rescore_kernel(
    const u32* __restrict__ cand, const u32* __restrict__ count,
    const float* __restrict__ x, const float* __restrict__ T,
    const float* __restrict__ rxn, u64* __restrict__ winner)
{
    u32 cnt = *count; if (cnt > CAND_MAX) cnt = CAND_MAX;
    if (blockIdx.x >= cnt) return;
    const u32 c = cand[blockIdx.x];
    const int row = c >> 10, strip = c & 1023;

    __shared__ float4 xs4[75];
    const int t = threadIdx.x;
    if (t < 75) xs4[t] = *(const float4*)&x[(size_t)row * D_ + t * 4];
    __syncthreads();

    const float rx = rxn[row];
    const int w = t >> 6, lane = t & 63;
    const int lane4 = lane & 3, colw = lane >> 2;   // 16 cols per wave-pass
    u64 best = 0ull;
    #pragma unroll
    for (int p = 0; p < 2; ++p) {
        const int n = strip * BN + w * 32 + p * 16 + colw;
        if (n < NT) {
            const float4* Tr = (const float4*)(T + (size_t)n * D_);
            float dot = 0.f, tt = 0.f;
            #pragma unroll
            for (int jj = 0; jj < 19; ++jj) {
                int idx = lane4 + jj * 4;
                if (idx < 75) {
                    float4 v = Tr[idx], xv = xs4[idx];
                    dot += v.x * xv.x + v.y * xv.y + v.z * xv.z + v.w * xv.w;
                    tt  += v.x * v.x + v.y * v.y + v.z * v.z + v.w * v.w;
                }
            }
            dot += __shfl_xor(dot, 1, 64); tt += __shfl_xor(tt, 1, 64);
            dot += __shfl_xor(dot, 2, 64); tt += __shfl_xor(tt, 2, 64);
            float sim = dot * rx / fmaxf(sqrtf(tt), EPS);
            u64 pk = ((u64)simkey(sim) << 32) | (u32)(~n);
            best = (pk > best) ? pk : best;
        }
    }
    #pragma unroll
    for (int m = 1; m < 64; m <<= 1) {
        u64 o = __shfl_xor(best, m, 64);
        best = (o > best) ? o : best;
    }
    if (lane == 0 && best) atomicMax(&winner[row], best);
}

// ---------------------------------------------------------------------------
// K5 "final": decode winner, fp64 rescore for score, label gather.
// ---------------------------------------------------------------------------
__global__ __launch_bounds__(64) void final_kernel(
    const u64* __restrict__ winner, const float* __restrict__ x,
    const float* __restrict__ T, const int* __restrict__ y_train,
    float* __restrict__ out)
{
    const int b = blockIdx.x;
    const int lane = threadIdx.x;
    int idx = (int)(~(u32)winner[b]);
    if (idx < 0 || idx >= NT) idx = 0;
    double dot = 0.0, nx = 0.0, nt = 0.0;
    for (int d = lane; d < D_; d += 64) {
        double xv = (double)x[(size_t)b * D_ + d];
        double tv = (double)T[(size_t)idx * D_ + d];
        dot += xv * tv; nx += xv * xv; nt += tv * tv;
    }
    #pragma unroll
    for (int m = 32; m >= 1; m >>= 1) {
        dot += __shfl_xor(dot, m, 64);
        nx  += __shfl_xor(nx, m, 64);
        nt  += __shfl_xor(nt, m, 64);
    }
    if (lane == 0) {
        double score = dot / (fmax(sqrt(nx), (double)EPS) * fmax(sqrt(nt), (double)EPS));
        out[b]      = (float)y_train[idx];
        out[B_ + b] = (float)score;
    }
}

// ---------------------------------------------------------------------------
extern "C" void kernel_launch(void* const* d_in, const int* in_sizes, int n_in,
                              void* d_out, int out_size, void* d_ws, size_t ws_size,
                              hipStream_t stream)
{
    const int*   ids = (const int*)d_in[0];
    const float* W   = (const float*)d_in[1];
    const float* T   = (const float*)d_in[2];
    const int*   y   = (const int*)d_in[3];

    char* ws = (char*)d_ws;
    size_t off = 0;
    float* x           = (float*)(ws + off);          off += (size_t)B_ * D_ * 4;        // 1,228,800
    unsigned short* xh = (unsigned short*)(ws + off); off += (size_t)B_ * DP * 2;        //   655,360
    float* rxn         = (float*)(ws + off);          off += (size_t)B_ * 4;             //     4,096
    unsigned short* Tb = (unsigned short*)(ws + off); off += (size_t)NTP * DP * 2;       // 64,225,280
    u32* blockmax      = (u32*)(ws + off);            off += (size_t)B_ * NSTRIP * 4;    //  3,211,264
    u32* cand          = (u32*)(ws + off);            off += (size_t)CAND_MAX * 4;       //     32,768
    u64* winner        = (u64*)(ws + off);            off += (size_t)B_ * 8;             //      8,192
    u32* count         = (u32*)(ws + off);            off += 256;                        // total ~69 MB

    prep_kernel<<<POOL_BLOCKS + TN_BLOCKS, 640, 0, stream>>>(ids, W, T, x, xh, rxn, Tb, count);
    gemm_hh_kernel<<<NSTRIP * 8, 256, 0, stream>>>(xh, Tb, blockmax);
    scan_kernel<<<B_, 256, 0, stream>>>(blockmax, cand, count, winner);
    rescore_kernel<<<CAND_MAX, 256, 0, stream>>>(cand, count, x, T, rxn, winner);
    final_kernel<<<B_, 64, 0, stream>>>(winner, x, T, y, (float*)d_out);
}

// Round 7
// 368.708 us; speedup vs baseline: 2.1887x; 1.0134x over previous
//
#include <hip/hip_runtime.h>
#include <hip/hip_bf16.h>
#include <stdint.h>

#define EPS 1e-8f

typedef __attribute__((ext_vector_type(8))) short bf16x8;
typedef __attribute__((ext_vector_type(4))) float f32x4;
typedef unsigned long long u64;
typedef unsigned int u32;

constexpr int SEQ = 200;
constexpr int B_  = 1024;    // batch
constexpr int D_  = 300;     // embedding dim
constexpr int DP  = 320;     // K padded
constexpr int NT  = 100000;  // train rows
constexpr int BM = 256, BN = 128, BK = 64;
constexpr int NSTRIP = 784;            // N strips (128 wide), multiple of 8
constexpr int NTP = NSTRIP * BN;       // 100352 padded rows
constexpr int POOL_BLOCKS = B_;        // 1024
constexpr int TN_BLOCKS = (NTP + 9) / 10;  // 10036 (10 rows/block @ 640 thr)
constexpr int CAND_MAX = 8192;
constexpr int RESCORE_BLOCKS = 2048;
#define MARGIN 2e-3f

__device__ __forceinline__ unsigned short f2bf(float f) {   // RNE
    u32 b = __float_as_uint(f);
    return (unsigned short)((b + 0x7fffu + ((b >> 16) & 1u)) >> 16);
}
__device__ __forceinline__ u32 simkey(float s) {            // order-preserving
    u32 b = __float_as_uint(s);
    return (b & 0x80000000u) ? ~b : (b | 0x80000000u);
}
__device__ __forceinline__ void gload_lds16(const void* g, void* l) {
    __builtin_amdgcn_global_load_lds(
        (const __attribute__((address_space(1))) unsigned int*)g,
        (__attribute__((address_space(3))) unsigned int*)l, 16, 0, 0);
}

// ---------------------------------------------------------------------------
// K1 "prep": fused pool (blocks 0..1023) + tnorm/convert (rest), 640 thr.
// Pool: 10 waves x 20 seq-rows each, float4 whole-row reads (chain depth 20),
// cross-wave LDS reduce. Writes x fp32, xh = bf16(x/||x||) (cols 300..319=0),
// rxn. Tnorm: 10 rows/block, writes Tb = bf16(t/||t||) (zero-padded).
// ---------------------------------------------------------------------------
__global__ __launch_bounds__(640) void prep_kernel(
    const int* __restrict__ ids, const float* __restrict__ W,
    const float* __restrict__ T,
    float* __restrict__ x, unsigned short* __restrict__ xh,
    float* __restrict__ rxn, unsigned short* __restrict__ Tb,
    u32* __restrict__ count)
{
    const int tid = threadIdx.x;
    const int w = tid >> 6, lane = tid & 63;
    if (blockIdx.x < POOL_BLOCKS) {
        // ----- pool path -----
        const int b = blockIdx.x;
        if (b == 0 && tid == 0) *count = 0;
        __shared__ int sid[SEQ];
        __shared__ float part[10 * 304];     // per-wave partial sums (12.2 KB)
        __shared__ float red[320];
        __shared__ float rns_s;
        for (int s = tid; s < SEQ; s += 640) sid[s] = ids[s * B_ + b];
        __syncthreads();
        float4 a0 = make_float4(0.f, 0.f, 0.f, 0.f);
        float4 a1 = make_float4(0.f, 0.f, 0.f, 0.f);
        for (int s = w; s < SEQ; s += 10) {
            const float4* Wr = (const float4*)(W + (size_t)sid[s] * D_);
            float4 v = Wr[lane];
            a0.x += v.x; a0.y += v.y; a0.z += v.z; a0.w += v.w;
            if (lane < 11) {
                float4 u = Wr[64 + lane];
                a1.x += u.x; a1.y += u.y; a1.z += u.z; a1.w += u.w;
            }
        }
        *(float4*)&part[w * 304 + lane * 4] = a0;              // dims 0..255
        if (lane < 11) *(float4*)&part[w * 304 + 256 + lane * 4] = a1;  // 256..299
        else if (lane == 11) {                                  // zero pad 300..303
            float4 z = make_float4(0.f, 0.f, 0.f, 0.f);
            *(float4*)&part[w * 304 + 256 + lane * 4] = z;
        }
        __syncthreads();
        float xv = 0.f;
        if (tid < 304) {
            float s = 0.f;
            #pragma unroll
            for (int ww = 0; ww < 10; ++ww) s += part[ww * 304 + tid];
            xv = s * (1.0f / SEQ);
        }
        if (tid < 320) red[tid] = (tid < D_) ? xv * xv : 0.f;
        __syncthreads();
        if (tid < 64) {
            float s = 0.f;
            #pragma unroll
            for (int i = 0; i < 5; ++i) s += red[tid + i * 64];
            #pragma unroll
            for (int m = 32; m >= 1; m >>= 1) s += __shfl_xor(s, m, 64);
            if (tid == 0) {
                float r = 1.0f / fmaxf(sqrtf(s), EPS);
                rxn[b] = r;
                rns_s = r;
            }
        }
        __syncthreads();
        const float rns = rns_s;
        if (tid < 320) {
            if (tid < D_) {
                x[(size_t)b * D_ + tid] = xv;
                xh[(size_t)b * DP + tid] = f2bf(xv * rns);
            } else {
                xh[(size_t)b * DP + tid] = 0;
            }
        }
    } else {
        // ----- tnorm/convert path: normalized bf16 rows -----
        const int n = (blockIdx.x - POOL_BLOCKS) * 10 + w;
        if (n >= NTP) return;
        ushort4* tb = (ushort4*)(Tb + (size_t)n * DP);   // 80 ushort4/row
        if (n >= NT) {
            ushort4 z = {0, 0, 0, 0};
            tb[lane] = z;
            if (lane < 16) tb[64 + lane] = z;
            return;
        }
        const float4* Tr = (const float4*)(T + (size_t)n * D_);
        float4 v = Tr[lane];
        float s = v.x * v.x + v.y * v.y + v.z * v.z + v.w * v.w;
        float4 w2 = make_float4(0.f, 0.f, 0.f, 0.f);
        if (lane < 11) {
            w2 = Tr[64 + lane];
            s += w2.x * w2.x + w2.y * w2.y + w2.z * w2.z + w2.w * w2.w;
        }
        #pragma unroll
        for (int m = 32; m >= 1; m >>= 1) s += __shfl_xor(s, m, 64);
        const float rns = 1.0f / fmaxf(sqrtf(s), EPS);
        ushort4 o;
        o.x = f2bf(v.x * rns); o.y = f2bf(v.y * rns);
        o.z = f2bf(v.z * rns); o.w = f2bf(v.w * rns);
        tb[lane] = o;
        if (lane < 16) {
            ushort4 p = {0, 0, 0, 0};
            if (lane < 11) {
                p.x = f2bf(w2.x * rns); p.y = f2bf(w2.y * rns);
                p.z = f2bf(w2.z * rns); p.w = f2bf(w2.w * rns);
            }
            tb[64 + lane] = p;
        }
    }
}

// ---------------------------------------------------------------------------
// K2: hh bf16 GEMM on normalized operands. 256x128 tile, 512 threads
// (8 waves, 4x2 of 64x64), launch_bounds(512,2) => 256-reg cap, NO spill
// (R4's (512,6) forced an 85-reg cap and spilled the accumulator).
// BK=64, global_load_lds width-16, xor-swizzled chunk pick. XCD swizzle:
// a strip's 4 M-blocks share g%8. Epilogue: float fmax, no atomics.
// ---------------------------------------------------------------------------
__global__ __launch_bounds__(512, 2) void gemm_hh_kernel(
    const unsigned short* __restrict__ Ah, const unsigned short* __restrict__ Tb,
    float* __restrict__ blockmax)
{
    __shared__ unsigned short sA[BM * BK];   // 32 KB
    __shared__ unsigned short sB[BN * BK];   // 16 KB
    __shared__ float sBestF[BM * 2];         // 2 KB

    const int tid = threadIdx.x;
    const int g = blockIdx.x;
    const int k8 = g & 7;
    const int h = g >> 3;
    const int bMi = h & 3;                       // M-tile (4)
    const int strip = ((h >> 2) << 3) | k8;      // same XCD for a strip's tiles

    const int lane = tid & 63, wid = tid >> 6;
    const int wm = wid >> 1, wn = wid & 1;       // 4 x 2 waves over 256 x 128
    const int quad = lane >> 4, l15 = lane & 15;

    const unsigned short* pA[4];
    int laA[4];
    #pragma unroll
    for (int j = 0; j < 4; ++j) {
        int L = (j * 8 + wid) * 64 + lane;       // 0..2047
        int r = L >> 3, c = (L & 7) ^ (r & 7);
        laA[j] = (j * 8 + wid) * 1024;
        pA[j] = Ah + (size_t)(bMi * BM + r) * DP + c * 8;
    }
    const unsigned short* pB[2];
    int laB[2];
    #pragma unroll
    for (int j = 0; j < 2; ++j) {
        int L = (j * 8 + wid) * 64 + lane;       // 0..1023
        int r = L >> 3, c = (L & 7) ^ (r & 7);
        laB[j] = (j * 8 + wid) * 1024;
        pB[j] = Tb + (size_t)(strip * BN + r) * DP + c * 8;
    }

    f32x4 acc[4][4] = {};

    for (int kp = 0; kp < DP; kp += BK) {
        #pragma unroll
        for (int j = 0; j < 4; ++j)
            gload_lds16(pA[j] + kp, (char*)sA + laA[j]);
        #pragma unroll
        for (int j = 0; j < 2; ++j)
            gload_lds16(pB[j] + kp, (char*)sB + laB[j]);
        __syncthreads();

        #pragma unroll
        for (int s = 0; s < 2; ++s) {
            bf16x8 fa[4], fb[4];
            #pragma unroll
            for (int f = 0; f < 4; ++f) {
                int ar = wm * 64 + f * 16 + l15;
                int ac = (s * 4 + quad) ^ (ar & 7);
                fa[f] = *(const bf16x8*)&sA[ar * BK + ac * 8];
                int br = wn * 64 + f * 16 + l15;
                int bc = (s * 4 + quad) ^ (br & 7);
                fb[f] = *(const bf16x8*)&sB[br * BK + bc * 8];
            }
            #pragma unroll
            for (int fm = 0; fm < 4; ++fm)
                #pragma unroll
                for (int fn = 0; fn < 4; ++fn)
                    acc[fm][fn] = __builtin_amdgcn_mfma_f32_16x16x32_bf16(
                        fa[fm], fb[fn], acc[fm][fn], 0, 0, 0);
        }
        __syncthreads();
    }

    // ---- epilogue: per-row fmax (acc is already the cosine), no atomics ----
    #pragma unroll
    for (int fm = 0; fm < 4; ++fm) {
        float v[4];
        #pragma unroll
        for (int r = 0; r < 4; ++r) {
            v[r] = fmaxf(fmaxf(acc[fm][0][r], acc[fm][1][r]),
                         fmaxf(acc[fm][2][r], acc[fm][3][r]));
        }
        #pragma unroll
        for (int m = 1; m < 16; m <<= 1) {
            #pragma unroll
            for (int r = 0; r < 4; ++r)
                v[r] = fmaxf(v[r], __shfl_xor(v[r], m, 64));
        }
        if (l15 == 0) {
            int rowbase = wm * 64 + fm * 16 + quad * 4;   // C row = quad*4+r
            #pragma unroll
            for (int r = 0; r < 4; ++r)
                sBestF[(rowbase + r) * 2 + wn] = v[r];
        }
    }
    __syncthreads();
    if (tid < BM)
        blockmax[(size_t)(bMi * BM + tid) * NSTRIP + strip] =
            fmaxf(sBestF[tid * 2], sBestF[tid * 2 + 1]);
}

// ---------------------------------------------------------------------------
// K3 "scan": per row, threshold = max(blockmax) - MARGIN; emit qualifying
// (row,strip) candidates; zero winner[row].
// ---------------------------------------------------------------------------
__global__ __launch_bounds__(256) void scan_kernel(
    const float* __restrict__ blockmax, u32* __restrict__ cand,
    u32* __restrict__ count, u64* __restrict__ winner)
{
    const int row = blockIdx.x;
    const int t = threadIdx.x;
    const int w = t >> 6, lane = t & 63;
    const float* bmr = blockmax + (size_t)row * NSTRIP;

    __shared__ float wred[4];
    __shared__ float thr_s;
    if (t == 0) winner[row] = 0ull;
    float m = -1e30f;
    for (int j = t; j < NSTRIP; j += 256) m = fmaxf(m, bmr[j]);
    #pragma unroll
    for (int msk = 32; msk >= 1; msk >>= 1) m = fmaxf(m, __shfl_xor(m, msk, 64));
    if (lane == 0) wred[w] = m;
    __syncthreads();
    if (t == 0) {
        float gmx = fmaxf(fmaxf(wred[0], wred[1]), fmaxf(wred[2], wred[3]));
        thr_s = gmx - MARGIN;
    }
    __syncthreads();
    const float thr = thr_s;
    for (int j = t; j < NSTRIP; j += 256) {
        if (bmr[j] >= thr) {
            u32 p = atomicAdd(count, 1u);
            if (p < CAND_MAX) cand[p] = ((u32)row << 10) | (u32)j;
        }
    }
}

// ---------------------------------------------------------------------------
// K4 "rescore": grid-stride over candidates; one block per candidate pass.
// Each wave: 16 cols concurrently (4 lanes/col), exact fp32; atomicMax winner.
// ---------------------------------------------------------------------------
__global__ __launch_bounds__(256) void rescore_kernel(
    const u32* __restrict__ cand, const u32* __restrict__ count,
    const float* __restrict__ x, const float* __restrict__ T,
    const float* __restrict__ rxn, u64* __restrict__ winner)
{
    u32 cnt = *count; if (cnt > CAND_MAX) cnt = CAND_MAX;
    __shared__ float4 xs4[75];
    const int t = threadIdx.x;
    const int w = t >> 6, lane = t & 63;
    const int lane4 = lane & 3, colw = lane >> 2;

    for (u32 ci = blockIdx.x; ci < cnt; ci += RESCORE_BLOCKS) {
        const u32 c = cand[ci];
        const int row = c >> 10, strip = c & 1023;
        __syncthreads();
        if (t < 75) xs4[t] = *(const float4*)&x[(size_t)row * D_ + t * 4];
        __syncthreads();
        const float rx = rxn[row];
        u64 best = 0ull;
        #pragma unroll
        for (int p = 0; p < 2; ++p) {
            const int n = strip * BN + w * 32 + p * 16 + colw;
            if (n < NT) {
                const float4* Tr = (const float4*)(T + (size_t)n * D_);
                float dot = 0.f, tt = 0.f;
                #pragma unroll
                for (int jj = 0; jj < 19; ++jj) {
                    int idx = lane4 + jj * 4;
                    if (idx < 75) {
                        float4 v = Tr[idx], xv = xs4[idx];
                        dot += v.x * xv.x + v.y * xv.y + v.z * xv.z + v.w * xv.w;
                        tt  += v.x * v.x + v.y * v.y + v.z * v.z + v.w * v.w;
                    }
                }
                dot += __shfl_xor(dot, 1, 64); tt += __shfl_xor(tt, 1, 64);
                dot += __shfl_xor(dot, 2, 64); tt += __shfl_xor(tt, 2, 64);
                float sim = dot * rx / fmaxf(sqrtf(tt), EPS);
                u64 pk = ((u64)simkey(sim) << 32) | (u32)(~n);
                best = (pk > best) ? pk : best;
            }
        }
        #pragma unroll
        for (int m = 1; m < 64; m <<= 1) {
            u64 o = __shfl_xor(best, m, 64);
            best = (o > best) ? o : best;
        }
        if (lane == 0 && best) atomicMax(&winner[row], best);
    }
}

// ---------------------------------------------------------------------------
// K5 "final": decode winner, fp64 rescore for score, label gather.
// ---------------------------------------------------------------------------
__global__ __launch_bounds__(64) void final_kernel(
    const u64* __restrict__ winner, const float* __restrict__ x,
    const float* __restrict__ T, const int* __restrict__ y_train,
    float* __restrict__ out)
{
    const int b = blockIdx.x;
    const int lane = threadIdx.x;
    int idx = (int)(~(u32)winner[b]);
    if (idx < 0 || idx >= NT) idx = 0;
    double dot = 0.0, nx = 0.0, nt = 0.0;
    for (int d = lane; d < D_; d += 64) {
        double xv = (double)x[(size_t)b * D_ + d];
        double tv = (double)T[(size_t)idx * D_ + d];
        dot += xv * tv; nx += xv * xv; nt += tv * tv;
    }
    #pragma unroll
    for (int m = 32; m >= 1; m >>= 1) {
        dot += __shfl_xor(dot, m, 64);
        nx  += __shfl_xor(nx, m, 64);
        nt  += __shfl_xor(nt, m, 64);
    }
    if (lane == 0) {
        double score = dot / (fmax(sqrt(nx), (double)EPS) * fmax(sqrt(nt), (double)EPS));
        out[b]      = (float)y_train[idx];
        out[B_ + b] = (float)score;
    }
}

// ---------------------------------------------------------------------------
extern "C" void kernel_launch(void* const* d_in, const int* in_sizes, int n_in,
                              void* d_out, int out_size, void* d_ws, size_t ws_size,
                              hipStream_t stream)
{
    const int*   ids = (const int*)d_in[0];
    const float* W   = (const float*)d_in[1];
    const float* T   = (const float*)d_in[2];
    const int*   y   = (const int*)d_in[3];

    char* ws = (char*)d_ws;
    size_t off = 0;
    float* x           = (float*)(ws + off);          off += (size_t)B_ * D_ * 4;        // 1,228,800
    unsigned short* xh = (unsigned short*)(ws + off); off += (size_t)B_ * DP * 2;        //   655,360
    float* rxn         = (float*)(ws + off);          off += (size_t)B_ * 4;             //     4,096
    unsigned short* Tb = (unsigned short*)(ws + off); off += (size_t)NTP * DP * 2;       // 64,225,280
    float* blockmax    = (float*)(ws + off);          off += (size_t)B_ * NSTRIP * 4;    //  3,211,264
    u32* cand          = (u32*)(ws + off);            off += (size_t)CAND_MAX * 4;       //     32,768
    u64* winner        = (u64*)(ws + off);            off += (size_t)B_ * 8;             //      8,192
    u32* count         = (u32*)(ws + off);            off += 256;                        // total ~69 MB

    prep_kernel<<<POOL_BLOCKS + TN_BLOCKS, 640, 0, stream>>>(ids, W, T, x, xh, rxn, Tb, count);
    gemm_hh_kernel<<<NSTRIP * 4, 512, 0, stream>>>(xh, Tb, blockmax);
    scan_kernel<<<B_, 256, 0, stream>>>(blockmax, cand, count, winner);
    rescore_kernel<<<RESCORE_BLOCKS, 256, 0, stream>>>(cand, count, x, T, rxn, winner);
    final_kernel<<<B_, 64, 0, stream>>>(winner, x, T, y, (float*)d_out);
}